// Round 3
// baseline (557.648 us; speedup 1.0000x reference)
//
#include <hip/hip_runtime.h>
#include <stdint.h>

// ---- problem constants ----
#define M_ROWS   224        // B*N = 32*7
#define K_DIM    49152      // D_MODEL*PATCH_NUMS
#define NCOL     1344       // 4 bands * 336
#define PRED     336
#define S_CHUNKS 48         // 21*48 = 1008 blocks = 3.94/CU (one round at 4 blk/CU)
#define STEPS    32         // K-steps of 32 per chunk: 1536/48

// ws layout: P (bf16 partials, 29 MB) at 0; Xbf16 (22 MB) at 32 MB
#define XB_OFFSET (32u * 1024u * 1024u)

typedef __attribute__((ext_vector_type(8))) short short8;
typedef __attribute__((ext_vector_type(4))) float floatx4;

__device__ __forceinline__ uint16_t f32_to_bf16(float f) {
    uint32_t u = __builtin_bit_cast(uint32_t, f);
    uint32_t r = (u + 0x7fffu + ((u >> 16) & 1u)) >> 16;   // RNE
    return (uint16_t)r;
}
__device__ __forceinline__ float bf16_to_f32(uint16_t h) {
    uint32_t u = ((uint32_t)h) << 16;
    return __builtin_bit_cast(float, u);
}
__device__ __forceinline__ uint32_t pack2(float lo, float hi) {
    return (uint32_t)f32_to_bf16(lo) | ((uint32_t)f32_to_bf16(hi) << 16);
}

// ======================= Kernel 0: X fp32 -> bf16 =======================
__global__ __launch_bounds__(256) void cvt_x(
    const float* __restrict__ X, uint16_t* __restrict__ Xb)
{
    const size_t i = ((size_t)blockIdx.x * 256 + threadIdx.x) * 8;
    const float4 a = *(const float4*)(X + i);
    const float4 b = *(const float4*)(X + i + 4);
    uint4 o;
    o.x = pack2(a.x, a.y);
    o.y = pack2(a.z, a.w);
    o.z = pack2(b.x, b.y);
    o.w = pack2(b.z, b.w);
    *(uint4*)(Xb + i) = o;
}

// ======================= Kernel 1: split-K GEMM, dbuf LDS, 1 barrier/step ====
// grid (21 col-tiles, 48 k-chunks), block 256 = 4 waves x 16 cols, full M=224.
// A staged via global_load_lds_dwordx4, fragment-ordered, DOUBLE buffered:
// glds(st+1) -> buf^1 overlaps MFMAs reading buf^0; one barrier per step.
__global__ __launch_bounds__(256, 4) void gemm_partial(
    const uint16_t* __restrict__ Xb,  // (224, 49152) bf16
    const float* __restrict__ W,      // (4, 49152, 336) fp32
    uint16_t* __restrict__ P)         // (224, 48, 1344) bf16 partials
{
    __shared__ uint16_t lA[2][14 * 512];     // 2 x 14 KB, fragment-ordered

    const int ct   = blockIdx.x;             // 0..20
    const int s    = blockIdx.y;             // 0..47
    const int tid  = threadIdx.x;
    const int lane = tid & 63;
    const int w    = tid >> 6;
    const int l15  = lane & 15;
    const int kq   = lane >> 4;
    const int c0w  = ct * 64 + w * 16;
    const int band = c0w / PRED;             // 16 | 336 -> no band straddle
    const int p0   = c0w - band * PRED;

    const float* wbase = W + (size_t)band * ((size_t)K_DIM * PRED)
                           + (size_t)(kq * 8) * PRED
                           + (size_t)(p0 + l15);
    const size_t grow = (size_t)l15 * K_DIM + (size_t)kq * 8;
    const int kbase = s * (STEPS * 32);      // chunk k-offset

    floatx4 acc[14];
    #pragma unroll
    for (int f = 0; f < 14; ++f) acc[f] = (floatx4){0.f, 0.f, 0.f, 0.f};

    float wcur[8], wnxt[8];

    // ---- prologue: W(0) and glds(0) -> buf0 ----
    #pragma unroll
    for (int j = 0; j < 8; ++j) wcur[j] = wbase[(size_t)(kbase + j) * PRED];
    #pragma unroll
    for (int t = 0; t < 4; ++t) {
        const int f = w + 4 * t;
        if (f < 14) {
            const uint16_t* gp = Xb + (size_t)(16 * f) * K_DIM + grow + kbase;
            __builtin_amdgcn_global_load_lds(
                (const __attribute__((address_space(1))) void*)gp,
                (__attribute__((address_space(3))) void*)&lA[0][f * 512],
                16, 0, 0);
        }
    }

    for (int st = 0; st < STEPS; ++st) {
        __syncthreads();   // drains glds(st)+W(st); fences buf^1 reads from st-1
        const int cur = st & 1;

        if (st + 1 < STEPS) {
            const int kn = kbase + (st + 1) * 32;
            #pragma unroll
            for (int t = 0; t < 4; ++t) {
                const int f = w + 4 * t;
                if (f < 14) {
                    const uint16_t* gp = Xb + (size_t)(16 * f) * K_DIM + grow + kn;
                    __builtin_amdgcn_global_load_lds(
                        (const __attribute__((address_space(1))) void*)gp,
                        (__attribute__((address_space(3))) void*)&lA[cur ^ 1][f * 512],
                        16, 0, 0);
                }
            }
            #pragma unroll
            for (int j = 0; j < 8; ++j) wnxt[j] = wbase[(size_t)(kn + j) * PRED];
        }

        short8 bfrag;
        #pragma unroll
        for (int j = 0; j < 4; ++j)
            ((uint32_t*)&bfrag)[j] = pack2(wcur[2 * j], wcur[2 * j + 1]);

        #pragma unroll
        for (int f = 0; f < 14; ++f) {
            short8 afrag = *(const short8*)&lA[cur][f * 512 + lane * 8];
            acc[f] = __builtin_amdgcn_mfma_f32_16x16x32_bf16(afrag, bfrag, acc[f], 0, 0, 0);
        }

        if (st + 1 < STEPS) {
            #pragma unroll
            for (int j = 0; j < 8; ++j) wcur[j] = wnxt[j];
        }
    }

    // ---- write bf16 partials: C/D layout col=lane&15, row=kq*4+reg ----
    const int col = c0w + l15;
    #pragma unroll
    for (int f = 0; f < 14; ++f) {
        #pragma unroll
        for (int r = 0; r < 4; ++r) {
            const int m = 16 * f + kq * 4 + r;
            P[((size_t)m * S_CHUNKS + s) * NCOL + col] = f32_to_bf16(acc[f][r]);
        }
    }
}

// ======================= Kernel 2: partial reduce + bias + iSWT =======================
__device__ const float REC_LO[8] = {
     0.23037781330885523f,  0.7148465705525415f,   0.6308807679295904f,
    -0.02798376941698385f, -0.18703481171888114f,  0.030841381835986965f,
     0.032883011666982945f, -0.010597401784997278f };
__device__ const float REC_HI[8] = {
     0.010597401784997278f, 0.032883011666982945f, -0.030841381835986965f,
    -0.18703481171888114f,  0.02798376941698385f,   0.6308807679295904f,
    -0.7148465705525415f,   0.23037781330885523f };

__global__ __launch_bounds__(1024) void reduce_iswt(
    const uint16_t* __restrict__ P,    // (224, 48, 1344) bf16
    const float* __restrict__ bias,    // (4, 336) flat == flat col
    float* __restrict__ out)           // (224, 336)
{
    __shared__ float coeff[NCOL];
    __shared__ float buf[2][PRED];

    const int row = blockIdx.x;
    const int tid = threadIdx.x;
    const uint32_t* pr = (const uint32_t*)(P + (size_t)row * S_CHUNKS * NCOL);

    if (tid < NCOL / 2) {
        float a0 = 0.f, a1 = 0.f;
        #pragma unroll 4
        for (int s = 0; s < S_CHUNKS; ++s) {
            const uint32_t v = pr[s * (NCOL / 2) + tid];
            a0 += bf16_to_f32((uint16_t)(v & 0xffff));
            a1 += bf16_to_f32((uint16_t)(v >> 16));
        }
        coeff[2 * tid]     = a0 + bias[2 * tid];
        coeff[2 * tid + 1] = a1 + bias[2 * tid + 1];
    }
    __syncthreads();

    if (tid < PRED) buf[0][tid] = coeff[tid];   // band 0 = cA
    __syncthreads();

    int curb = 0;
    for (int j = 3; j >= 1; --j) {
        const int step = 1 << (j - 1);              // 4, 2, 1
        const int M    = PRED / step;               // 84, 168, 336
        const float* cd  = &coeff[(4 - j) * PRED];  // cD3, cD2, cD1
        const float* cur = buf[curb];
        float* nxt       = buf[curb ^ 1];
        if (tid < PRED) {
            const int t = tid;
            const int sidx = t & (step - 1);
            const int m = t / step;
            const int mm1 = (m == 0) ? (M - 1) : (m - 1);
            float x1 = 0.f, x2 = 0.f;
            #pragma unroll
            for (int k = 0; k < 8; ++k) {
                int i1 = m + 3 - k;  if (i1 < 0) i1 += M; else if (i1 >= M) i1 -= M;
                if ((i1 & 1) == 0) {
                    const int pos = i1 * step + sidx;
                    x1 += cur[pos] * REC_LO[k] + cd[pos] * REC_HI[k];
                }
                int i2 = mm1 + 3 - k;  if (i2 < 0) i2 += M; else if (i2 >= M) i2 -= M;
                if ((i2 & 1) == 0) {
                    const int pos = (i2 + 1) * step + sidx;
                    x2 += cur[pos] * REC_LO[k] + cd[pos] * REC_HI[k];
                }
            }
            nxt[t] = 0.5f * (x1 + x2);
        }
        __syncthreads();
        curb ^= 1;
    }

    if (tid < PRED) out[(size_t)row * PRED + tid] = buf[curb][tid];
}

// ======================= launch =======================
// MEASUREMENT ROUND: the whole kernel chain is dispatched TWICE (identical,
// deterministic). delta(total) vs single-pass = exact kernel-chain duration,
// separating harness restore/poison overhead from our kernels.
extern "C" void kernel_launch(void* const* d_in, const int* in_sizes, int n_in,
                              void* d_out, int out_size, void* d_ws, size_t ws_size,
                              hipStream_t stream) {
    const float* X    = (const float*)d_in[0];   // (224, 49152)
    const float* W    = (const float*)d_in[1];   // (4, 49152, 336)
    const float* bias = (const float*)d_in[2];   // (4, 336)
    float* out        = (float*)d_out;           // (224, 336)
    uint16_t* P       = (uint16_t*)d_ws;                          // 29 MB partials
    uint16_t* Xb      = (uint16_t*)((char*)d_ws + XB_OFFSET);     // 22 MB bf16 X

    for (int rep = 0; rep < 2; ++rep) {
        cvt_x       <<<5376, 256, 0, stream>>>(X, Xb);
        gemm_partial<<<dim3(21, S_CHUNKS), 256, 0, stream>>>(Xb, W, P);
        reduce_iswt <<<M_ROWS, 1024, 0, stream>>>(P, bias, out);
    }
}

// Round 4
// 428.315 us; speedup vs baseline: 1.3020x; 1.3020x over previous
//
#include <hip/hip_runtime.h>
#include <stdint.h>

// ---- problem constants ----
#define M_ROWS   224        // B*N = 32*7
#define K_DIM    49152      // D_MODEL*PATCH_NUMS
#define NCOL     1344       // 4 bands * 336
#define PRED     336
#define S_CHUNKS 48         // 21*48 = 1008 blocks = 3.94/CU
#define STEPS    32         // K-steps of 32 per chunk: 1536/48

// ws layout: P (bf16 partials, 29 MB) at 0; Xbf16 (22 MB) at 32 MB
#define XB_OFFSET (32u * 1024u * 1024u)

typedef __attribute__((ext_vector_type(8))) short short8;
typedef __attribute__((ext_vector_type(4))) float floatx4;

__device__ __forceinline__ uint16_t f32_to_bf16(float f) {
    uint32_t u = __builtin_bit_cast(uint32_t, f);
    uint32_t r = (u + 0x7fffu + ((u >> 16) & 1u)) >> 16;   // RNE
    return (uint16_t)r;
}
__device__ __forceinline__ float bf16_to_f32(uint16_t h) {
    uint32_t u = ((uint32_t)h) << 16;
    return __builtin_bit_cast(float, u);
}
__device__ __forceinline__ uint32_t pack2(float lo, float hi) {
    return (uint32_t)f32_to_bf16(lo) | ((uint32_t)f32_to_bf16(hi) << 16);
}

// ======================= Kernel 0: X fp32 -> bf16 =======================
__global__ __launch_bounds__(256) void cvt_x(
    const float* __restrict__ X, uint16_t* __restrict__ Xb)
{
    const size_t i = ((size_t)blockIdx.x * 256 + threadIdx.x) * 8;
    const float4 a = *(const float4*)(X + i);
    const float4 b = *(const float4*)(X + i + 4);
    uint4 o;
    o.x = pack2(a.x, a.y);
    o.y = pack2(a.z, a.w);
    o.z = pack2(b.x, b.y);
    o.w = pack2(b.z, b.w);
    *(uint4*)(Xb + i) = o;
}

// ======================= Kernel 1: split-K GEMM, dbuf LDS, XCD-swizzled ====
// 1008 blocks (1-D). Swizzle: id&7 ~ XCD (round-robin dispatch); all 21
// col-tiles of a K-chunk s land on one XCD -> the 458 KB A-chunk is read
// from HBM once per XCD and served 21x from its private L2 (6 chunks/XCD
// = 2.75 MB working set < 4 MB L2).
__global__ __launch_bounds__(256, 4) void gemm_partial(
    const uint16_t* __restrict__ Xb,  // (224, 49152) bf16
    const float* __restrict__ W,      // (4, 49152, 336) fp32
    uint16_t* __restrict__ P)         // (224, 48, 1344) bf16 partials
{
    __shared__ uint16_t lA[2][14 * 512];     // 2 x 14 KB, fragment-ordered

    const int id = blockIdx.x;
    const int g  = id & 7;                   // presumed XCD
    const int q  = id >> 3;                  // 0..125
    const int ct = q % 21;                   // col-tile 0..20
    const int s  = g + 8 * (q / 21);         // K-chunk 0..47, s%8 == XCD

    const int tid  = threadIdx.x;
    const int lane = tid & 63;
    const int w    = tid >> 6;
    const int l15  = lane & 15;
    const int kq   = lane >> 4;
    const int c0w  = ct * 64 + w * 16;
    const int band = c0w / PRED;             // 16 | 336 -> no band straddle
    const int p0   = c0w - band * PRED;

    const float* wbase = W + (size_t)band * ((size_t)K_DIM * PRED)
                           + (size_t)(kq * 8) * PRED
                           + (size_t)(p0 + l15);
    const size_t grow = (size_t)l15 * K_DIM + (size_t)kq * 8;
    const int kbase = s * (STEPS * 32);

    floatx4 acc[14];
    #pragma unroll
    for (int f = 0; f < 14; ++f) acc[f] = (floatx4){0.f, 0.f, 0.f, 0.f};

    float wcur[8], wnxt[8];

    // ---- prologue: W(0) and glds(0) -> buf0 ----
    #pragma unroll
    for (int j = 0; j < 8; ++j) wcur[j] = wbase[(size_t)(kbase + j) * PRED];
    #pragma unroll
    for (int t = 0; t < 4; ++t) {
        const int f = w + 4 * t;
        if (f < 14) {
            const uint16_t* gp = Xb + (size_t)(16 * f) * K_DIM + grow + kbase;
            __builtin_amdgcn_global_load_lds(
                (const __attribute__((address_space(1))) void*)gp,
                (__attribute__((address_space(3))) void*)&lA[0][f * 512],
                16, 0, 0);
        }
    }

    for (int st = 0; st < STEPS; ++st) {
        __syncthreads();   // drains glds(st)+W(st); fences buf^1 reads from st-1
        const int cur = st & 1;

        if (st + 1 < STEPS) {
            const int kn = kbase + (st + 1) * 32;
            #pragma unroll
            for (int t = 0; t < 4; ++t) {
                const int f = w + 4 * t;
                if (f < 14) {
                    const uint16_t* gp = Xb + (size_t)(16 * f) * K_DIM + grow + kn;
                    __builtin_amdgcn_global_load_lds(
                        (const __attribute__((address_space(1))) void*)gp,
                        (__attribute__((address_space(3))) void*)&lA[cur ^ 1][f * 512],
                        16, 0, 0);
                }
            }
            #pragma unroll
            for (int j = 0; j < 8; ++j) wnxt[j] = wbase[(size_t)(kn + j) * PRED];
        }

        short8 bfrag;
        #pragma unroll
        for (int j = 0; j < 4; ++j)
            ((uint32_t*)&bfrag)[j] = pack2(wcur[2 * j], wcur[2 * j + 1]);

        #pragma unroll
        for (int f = 0; f < 14; ++f) {
            short8 afrag = *(const short8*)&lA[cur][f * 512 + lane * 8];
            acc[f] = __builtin_amdgcn_mfma_f32_16x16x32_bf16(afrag, bfrag, acc[f], 0, 0, 0);
        }

        if (st + 1 < STEPS) {
            #pragma unroll
            for (int j = 0; j < 8; ++j) wcur[j] = wnxt[j];
        }
    }

    // ---- write bf16 partials: C/D layout col=lane&15, row=kq*4+reg ----
    const int col = c0w + l15;
    #pragma unroll
    for (int f = 0; f < 14; ++f) {
        #pragma unroll
        for (int r = 0; r < 4; ++r) {
            const int m = 16 * f + kq * 4 + r;
            P[((size_t)m * S_CHUNKS + s) * NCOL + col] = f32_to_bf16(acc[f][r]);
        }
    }
}

// ======================= Kernel 2: partial reduce + bias + iSWT =======================
__device__ const float REC_LO[8] = {
     0.23037781330885523f,  0.7148465705525415f,   0.6308807679295904f,
    -0.02798376941698385f, -0.18703481171888114f,  0.030841381835986965f,
     0.032883011666982945f, -0.010597401784997278f };
__device__ const float REC_HI[8] = {
     0.010597401784997278f, 0.032883011666982945f, -0.030841381835986965f,
    -0.18703481171888114f,  0.02798376941698385f,   0.6308807679295904f,
    -0.7148465705525415f,   0.23037781330885523f };

__global__ __launch_bounds__(1024) void reduce_iswt(
    const uint16_t* __restrict__ P,    // (224, 48, 1344) bf16
    const float* __restrict__ bias,    // (4, 336) flat == flat col
    float* __restrict__ out)           // (224, 336)
{
    __shared__ float coeff[NCOL];
    __shared__ float buf[2][PRED];

    const int row = blockIdx.x;
    const int tid = threadIdx.x;
    const uint32_t* pr = (const uint32_t*)(P + (size_t)row * S_CHUNKS * NCOL);

    if (tid < NCOL / 2) {
        float a0 = 0.f, a1 = 0.f;
        #pragma unroll 4
        for (int s = 0; s < S_CHUNKS; ++s) {
            const uint32_t v = pr[s * (NCOL / 2) + tid];
            a0 += bf16_to_f32((uint16_t)(v & 0xffff));
            a1 += bf16_to_f32((uint16_t)(v >> 16));
        }
        coeff[2 * tid]     = a0 + bias[2 * tid];
        coeff[2 * tid + 1] = a1 + bias[2 * tid + 1];
    }
    __syncthreads();

    if (tid < PRED) buf[0][tid] = coeff[tid];   // band 0 = cA
    __syncthreads();

    int curb = 0;
    for (int j = 3; j >= 1; --j) {
        const int step = 1 << (j - 1);              // 4, 2, 1
        const int M    = PRED / step;               // 84, 168, 336
        const float* cd  = &coeff[(4 - j) * PRED];  // cD3, cD2, cD1
        const float* cur = buf[curb];
        float* nxt       = buf[curb ^ 1];
        if (tid < PRED) {
            const int t = tid;
            const int sidx = t & (step - 1);
            const int m = t / step;
            const int mm1 = (m == 0) ? (M - 1) : (m - 1);
            float x1 = 0.f, x2 = 0.f;
            #pragma unroll
            for (int k = 0; k < 8; ++k) {
                int i1 = m + 3 - k;  if (i1 < 0) i1 += M; else if (i1 >= M) i1 -= M;
                if ((i1 & 1) == 0) {
                    const int pos = i1 * step + sidx;
                    x1 += cur[pos] * REC_LO[k] + cd[pos] * REC_HI[k];
                }
                int i2 = mm1 + 3 - k;  if (i2 < 0) i2 += M; else if (i2 >= M) i2 -= M;
                if ((i2 & 1) == 0) {
                    const int pos = (i2 + 1) * step + sidx;
                    x2 += cur[pos] * REC_LO[k] + cd[pos] * REC_HI[k];
                }
            }
            nxt[t] = 0.5f * (x1 + x2);
        }
        __syncthreads();
        curb ^= 1;
    }

    if (tid < PRED) out[(size_t)row * PRED + tid] = buf[curb][tid];
}

// ======================= launch =======================
extern "C" void kernel_launch(void* const* d_in, const int* in_sizes, int n_in,
                              void* d_out, int out_size, void* d_ws, size_t ws_size,
                              hipStream_t stream) {
    const float* X    = (const float*)d_in[0];   // (224, 49152)
    const float* W    = (const float*)d_in[1];   // (4, 49152, 336)
    const float* bias = (const float*)d_in[2];   // (4, 336)
    float* out        = (float*)d_out;           // (224, 336)
    uint16_t* P       = (uint16_t*)d_ws;                          // 29 MB partials
    uint16_t* Xb      = (uint16_t*)((char*)d_ws + XB_OFFSET);     // 22 MB bf16 X

    cvt_x       <<<5376, 256, 0, stream>>>(X, Xb);
    gemm_partial<<<21 * S_CHUNKS, 256, 0, stream>>>(Xb, W, P);
    reduce_iswt <<<M_ROWS, 1024, 0, stream>>>(P, bias, out);
}